// Round 3
// baseline (249.859 us; speedup 1.0000x reference)
//
#include <hip/hip_runtime.h>
#include <hip/hip_fp16.h>

// Capsule dynamic routing, fully fused into ONE kernel (plain launch).
// x:[B,I,K]=32x2048x8, W:[J,I,D,K]=32x2048x16x8, out v:[B,J,D]=32x32x16.
// R8: R7's barrier used ONE atomic counter line -> 256 serialized cross-XCD
// atomics (~20us/barrier x5 ~= the 100us idle; VALUBusy 13%). Replaced with
// distributed arrival: each block release-stores gen into its OWN 128B slot
// (parallel), block 0 wave 0 polls all 256 slots then release-stores a flag,
// others poll the flag. Also: plain <<<>>> launch instead of cooperative
// (R1/R2 both showed ~70us coop-dispatch overhead inside the graph; with
// 512 thr / 72.7KB LDS / 124 VGPR and grid==256==#CUs, co-residency holds
// by capacity: LDS cannot fit 2 blocks/CU). Compute identical to R7.

#define ICAP    2048
#define JD      512          // JCAP*DDIM
#define S_ELEMS 16384        // BATCH*JCAP*DDIM
#define EPSQ    1e-7f
#define NBP     256          // blocks (one 8-i chunk each)
#define ICH     8            // i's per block
#define WROW    1040         // 64 slots x 16B + 16B pad (bank rotation on stage)
#define WIL     (8 * WROW)   // per-il LDS bytes (8 d_local rows)

// gbar layout (unsigned words): word 0 = release flag (own 128B line);
// words 32 + b*32 = block b's arrival slot (one 128B line each).
#define GBAR_WORDS (32 + NBP * 32)

typedef _Float16 h2v __attribute__((ext_vector_type(2)));
union H8 { int4 i4; h2v h[4]; };

#if defined(__has_builtin) && __has_builtin(__builtin_amdgcn_fdot2)
#define FDOT2(a, b, c) __builtin_amdgcn_fdot2((a), (b), (c), false)
#else
__device__ inline float FDOT2(h2v a, h2v b, float c) {
    return c + (float)a[0] * (float)b[0] + (float)a[1] * (float)b[1];
}
#endif
#if defined(__has_builtin) && __has_builtin(__builtin_amdgcn_rcpf)
#define FAST_RCP(x) __builtin_amdgcn_rcpf(x)
#else
#define FAST_RCP(x) (1.0f / (x))
#endif
#if defined(__has_builtin) && __has_builtin(__builtin_amdgcn_rsqf)
#define FAST_RSQ(x) __builtin_amdgcn_rsqf(x)
#else
#define FAST_RSQ(x) rsqrtf(x)
#endif

// ---------------------------------------------------------------------------
// Distributed-arrival grid barrier. Requires co-resident grid and zeroed
// state. Generations are 1-based and monotone within a launch.
// Visibility: writer fence + release slot-store; checker acquire slot-loads
// + release flag-store (transitive); pollers acquire flag-load; __syncthreads
// fans ordering out to the block (1 block/CU: the acquire's cache inv acts
// CU-wide).
// ---------------------------------------------------------------------------
__device__ __forceinline__ void gsync(unsigned* gb, unsigned gen,
                                      int bid, int tid) {
    __syncthreads();
    if (tid == 0) {
        __threadfence();     // prior global stores ordered before arrival
        __hip_atomic_store(gb + 32 + bid * 32, gen, __ATOMIC_RELEASE,
                           __HIP_MEMORY_SCOPE_AGENT);
    }
    if (bid == 0) {
        if (tid < 64) {
            const unsigned* s = gb + 32 + tid * 32;
            for (;;) {
                bool done = true;
#pragma unroll
                for (int q = 0; q < 4; ++q) {
                    const unsigned v = __hip_atomic_load(
                        s + q * 64 * 32, __ATOMIC_ACQUIRE,
                        __HIP_MEMORY_SCOPE_AGENT);
                    done &= (v >= gen);
                }
                if (__all(done)) break;
                __builtin_amdgcn_s_sleep(1);
            }
            if (tid == 0)
                __hip_atomic_store(gb, gen, __ATOMIC_RELEASE,
                                   __HIP_MEMORY_SCOPE_AGENT);
        }
    } else {
        if (tid == 0) {
            for (;;) {
                const unsigned r = __hip_atomic_load(
                    gb, __ATOMIC_ACQUIRE, __HIP_MEMORY_SCOPE_AGENT);
                if (r >= gen) break;
                __builtin_amdgcn_s_sleep(2);
            }
        }
    }
    __syncthreads();
}

// ---------------------------------------------------------------------------
// Fused kernel: 256 blocks x 512 threads (8 waves), 1 block/CU.
// Wave w owns b in {w, w+8, w+16, w+24}; lane l -> j = l&31, dh = l>>5.
// LDS: sWt 66.5KB (f16 W chunk, pass layout, 16B pad/row), sX 4KB, rbuf 2KB.
// ---------------------------------------------------------------------------
__global__ __launch_bounds__(512, 1)
void caps_fused(const float4* __restrict__ Wv, const float4* __restrict__ Xv,
                float* __restrict__ vsum, __half* __restrict__ partials,
                float* __restrict__ out, unsigned* __restrict__ gbar)
{
    __shared__ __align__(16) unsigned char sWt[WIL * ICH];   // 66560 B
    __shared__ __align__(16) unsigned char sX[4096];         // 32b x 8il x 16B
    __shared__ float rbuf[8][64];

    const int tid = threadIdx.x;
    const int bid = blockIdx.x;
    const int i0  = bid * ICH;

    // ---- stage W: fp32 global -> f16 LDS in pass layout ----
    // slot (il, d&7 row, s=2j+dh) holds W[j, i0+il, d, k=0..7] as 8 halves.
#pragma unroll
    for (int it = 0; it < 16; ++it) {
        const int f  = it * 512 + tid;          // [0, 8192) float4s
        const int q4 = f & 31;                  // float4 within (j,il) row
        const int il = (f >> 5) & 7;
        const int jj = f >> 8;
        const float4 w = Wv[((size_t)jj * ICAP + (i0 + il)) * 32 + q4];
        ushort4 h;
        h.x = __half_as_ushort(__float2half(w.x));
        h.y = __half_as_ushort(__float2half(w.y));
        h.z = __half_as_ushort(__float2half(w.z));
        h.w = __half_as_ushort(__float2half(w.w));
        const int d   = q4 >> 1;
        const int sub = q4 & 1;
        *reinterpret_cast<ushort4*>(sWt + il * WIL + (d & 7) * WROW
                                    + (2 * jj + (d >> 3)) * 16 + sub * 8) = h;
    }
    // ---- stage x: fp32 global -> f16 LDS, slot (b*8+il)*16B = x[b,i,0..7] ----
    {
        const int k4 = tid & 1, il = (tid >> 1) & 7, b = tid >> 4;
        const float4 w = Xv[((size_t)b * ICAP + (i0 + il)) * 2 + k4];
        ushort4 h;
        h.x = __half_as_ushort(__float2half(w.x));
        h.y = __half_as_ushort(__float2half(w.y));
        h.z = __half_as_ushort(__float2half(w.z));
        h.w = __half_as_ushort(__float2half(w.w));
        *reinterpret_cast<ushort4*>(sX + (b * 8 + il) * 16 + k4 * 8) = h;
    }
    __syncthreads();

    const int wave = tid >> 6, lane = tid & 63;
    const int j = lane & 31, dh = lane >> 5;
    float vacc = 0.f;                            // wave-0: running vsum[e]

#pragma unroll
    for (int r = 0; r < 3; ++r) {
        const bool first = (r == 0);             // constant after unroll
        float vs[4][8], sacc[4][8];
#pragma unroll
        for (int bb = 0; bb < 4; ++bb) {
            const int b = wave + 8 * bb;
            if (!first) {
                const float* vp = vsum + b * JD + j * 16 + dh * 8;
                const float4 a  = *reinterpret_cast<const float4*>(vp);
                const float4 bq = *reinterpret_cast<const float4*>(vp + 4);
                vs[bb][0]=a.x; vs[bb][1]=a.y; vs[bb][2]=a.z; vs[bb][3]=a.w;
                vs[bb][4]=bq.x; vs[bb][5]=bq.y; vs[bb][6]=bq.z; vs[bb][7]=bq.w;
            }
#pragma unroll
            for (int q = 0; q < 8; ++q) sacc[bb][q] = 0.f;
        }

#pragma unroll
        for (int il = 0; il < ICH; ++il) {
            H8 w8[8];
#pragma unroll
            for (int cc = 0; cc < 8; ++cc)
                w8[cc].i4 = *reinterpret_cast<const int4*>(
                    sWt + il * WIL + cc * WROW + (2 * j + dh) * 16);
#pragma unroll
            for (int bb = 0; bb < 4; ++bb) {
                const int b = wave + 8 * bb;
                H8 xv;
                xv.i4 = *reinterpret_cast<const int4*>(sX + (b * 8 + il) * 16);

                float u[8], tpart = 0.f;
#pragma unroll
                for (int q = 0; q < 8; ++q) {
                    float acc = FDOT2(w8[q].h[0], xv.h[0], 0.f);
                    acc = FDOT2(w8[q].h[1], xv.h[1], acc);
                    acc = FDOT2(w8[q].h[2], xv.h[2], acc);
                    acc = FDOT2(w8[q].h[3], xv.h[3], acc);
                    u[q] = acc;
                    if (!first) tpart = fmaf(acc, vs[bb][q], tpart);
                }
                float c;
                if (first) {
                    c = 0.03125f;                // softmax(0) over 32 j's
                } else {
                    const float t = tpart + __shfl_xor(tpart, 32);
                    const float e = __expf(t);
                    float se = e;
#pragma unroll
                    for (int off = 1; off <= 16; off <<= 1)
                        se += __shfl_xor(se, off);
                    c = e * FAST_RCP(se);
                }
#pragma unroll
                for (int q = 0; q < 8; ++q)
                    sacc[bb][q] = fmaf(c, u[q], sacc[bb][q]);
            }
        }

        // fp16 partial slice, disjoint per block
        __half* pout = partials + (size_t)bid * S_ELEMS;
#pragma unroll
        for (int bb = 0; bb < 4; ++bb) {
            const int b = wave + 8 * bb;
            union { int4 v; __half2 h[4]; } pk;
#pragma unroll
            for (int q = 0; q < 4; ++q)
                pk.h[q] = __floats2half2_rn(sacc[bb][2 * q], sacc[bb][2 * q + 1]);
            *reinterpret_cast<int4*>(pout + b * JD + j * 16 + dh * 8) = pk.v;
        }

        gsync(gbar, 2 * r + 1, bid, tid);

        // ---- reduce: block owns e in [bid*64, bid*64+64) ----
        {
            const int e = bid * 64 + lane;
            float s = 0.f;
            const __half* p = partials + (size_t)wave * 32 * S_ELEMS + e;
#pragma unroll
            for (int n = 0; n < 32; ++n)
                s += __half2float(p[(size_t)n * S_ELEMS]);
            rbuf[wave][lane] = s;
            __syncthreads();
            if (wave == 0) {
                s = 0.f;
#pragma unroll
                for (int k = 0; k < 8; ++k) s += rbuf[k][lane];
                float n2 = s * s;
#pragma unroll
                for (int off = 1; off <= 8; off <<= 1)
                    n2 += __shfl_xor(n2, off);
                const float scale = n2 * FAST_RCP(1.f + n2) * FAST_RSQ(n2 + EPSQ);
                const float v = s * scale;
                if (r == 2) {
                    out[e] = v;
                } else {
                    vacc += v;                   // vsum = sum of v's so far
                    vsum[e] = vacc;
                }
            }
        }
        if (r < 2) gsync(gbar, 2 * r + 2, bid, tid);
    }
}

extern "C" void kernel_launch(void* const* d_in, const int* in_sizes, int n_in,
                              void* d_out, int out_size, void* d_ws, size_t ws_size,
                              hipStream_t stream) {
    const float* x = (const float*)d_in[0];   // [32,2048,8]
    const float* W = (const float*)d_in[1];   // [32,2048,16,8]
    float* out = (float*)d_out;               // [32,32,16]

    // ws: vsum 64KB | partials fp16 8.39MB | gbar 33KB
    float*    vsum     = (float*)d_ws;
    __half*   partials = (__half*)((char*)d_ws + 65536);
    unsigned* gbar     = (unsigned*)((char*)partials + (size_t)NBP * S_ELEMS * 2);

    // zero barrier state (flag line + 256 arrival slots)
    hipMemsetAsync(gbar, 0, GBAR_WORDS * sizeof(unsigned), stream);

    caps_fused<<<NBP, 512, 0, stream>>>((const float4*)W, (const float4*)x,
                                        vsum, partials, out, gbar);
}

// Round 4
// 176.598 us; speedup vs baseline: 1.4148x; 1.4148x over previous
//
#include <hip/hip_runtime.h>
#include <hip/hip_fp16.h>

// Capsule dynamic routing, fully fused into ONE kernel (plain launch).
// x:[B,I,K]=32x2048x8, W:[J,I,D,K]=32x2048x16x8, out v:[B,J,D]=32x32x16.
// R9: R8 (plain launch) regressed vs R7 (coop) 147->227us because plain
// dispatch may PACK 2 blocks/CU (2x72704 LDS = 145KB < 160KB fits!) leaving
// other CUs idle; every barrier then waits for the half-speed stragglers.
// Coop launch avoided that by even placement but costs ~60-70us of graph
// overhead (R7/R8 end-to-end gaps: 82us vs 23us). Fix: pad static LDS to
// 87040B so 2 blocks/CU physically cannot fit -> plain launch is forced to
// 1 block/CU (grid==256==#CUs), giving coop placement without coop cost.
// Barrier spins relaxed + single acquire fence at exit; arrival is a
// release-store to the block's own 128B slot (no RMW serialization).
// Compute is bit-identical to R6/R7/R8.

#define ICAP    2048
#define JD      512          // JCAP*DDIM
#define S_ELEMS 16384        // BATCH*JCAP*DDIM
#define EPSQ    1e-7f
#define NBP     256          // blocks (one 8-i chunk each)
#define ICH     8            // i's per block
#define WROW    1040         // 64 slots x 16B + 16B pad (bank rotation on stage)
#define WIL     (8 * WROW)   // per-il LDS bytes (8 d_local rows)

// gbar layout (unsigned words): word 0 = release flag (own 128B line);
// words 32 + b*32 = block b's arrival slot (one 128B line each).
#define GBAR_WORDS (32 + NBP * 32)

typedef _Float16 h2v __attribute__((ext_vector_type(2)));
union H8 { int4 i4; h2v h[4]; };

#if defined(__has_builtin) && __has_builtin(__builtin_amdgcn_fdot2)
#define FDOT2(a, b, c) __builtin_amdgcn_fdot2((a), (b), (c), false)
#else
__device__ inline float FDOT2(h2v a, h2v b, float c) {
    return c + (float)a[0] * (float)b[0] + (float)a[1] * (float)b[1];
}
#endif
#if defined(__has_builtin) && __has_builtin(__builtin_amdgcn_rcpf)
#define FAST_RCP(x) __builtin_amdgcn_rcpf(x)
#else
#define FAST_RCP(x) (1.0f / (x))
#endif
#if defined(__has_builtin) && __has_builtin(__builtin_amdgcn_rsqf)
#define FAST_RSQ(x) __builtin_amdgcn_rsqf(x)
#else
#define FAST_RSQ(x) rsqrtf(x)
#endif

// ---------------------------------------------------------------------------
// Distributed-arrival grid barrier. Requires co-resident grid (enforced by
// LDS capacity: 1 block/CU, grid == #CUs) and zeroed state. Generations are
// 1-based, monotone within a launch. Visibility: writer __threadfence +
// slot store (agent scope); checker relaxed-polls all 256 slots, fences
// (acquire), publishes flag; pollers relaxed-spin on flag then fence.
// Relaxed agent-scope atomics still bypass stale caches (visibility is
// scope-, not ordering-, determined); the fences supply ordering once.
// ---------------------------------------------------------------------------
__device__ __forceinline__ void gsync(unsigned* gb, unsigned gen,
                                      int bid, int tid) {
    __syncthreads();
    if (tid == 0) {
        __threadfence();     // release: prior global stores before arrival
        __hip_atomic_store(gb + 32 + bid * 32, gen, __ATOMIC_RELAXED,
                           __HIP_MEMORY_SCOPE_AGENT);
    }
    if (bid == 0) {
        if (tid < 64) {
            const unsigned* s = gb + 32 + tid * 32;
            for (;;) {
                bool done = true;
#pragma unroll
                for (int q = 0; q < 4; ++q) {
                    const unsigned v = __hip_atomic_load(
                        s + q * 2048, __ATOMIC_RELAXED,
                        __HIP_MEMORY_SCOPE_AGENT);
                    done &= (v >= gen);
                }
                if (__all(done)) break;
                __builtin_amdgcn_s_sleep(1);
            }
            __threadfence(); // acquire side (transitivity to flag store)
            if (tid == 0)
                __hip_atomic_store(gb, gen, __ATOMIC_RELAXED,
                                   __HIP_MEMORY_SCOPE_AGENT);
        }
    } else if (tid == 0) {
        while (__hip_atomic_load(gb, __ATOMIC_RELAXED,
                                 __HIP_MEMORY_SCOPE_AGENT) < gen)
            __builtin_amdgcn_s_sleep(8);
        __threadfence();     // acquire
    }
    __syncthreads();
}

// ---------------------------------------------------------------------------
// Fused kernel: 256 blocks x 512 threads (8 waves), 1 block/CU (LDS-forced).
// Wave w owns b in {w, w+8, w+16, w+24}; lane l -> j = l&31, dh = l>>5.
// LDS: sWt 66.5KB (f16 W chunk, pass layout, 16B pad/row), sX 4KB,
// rbuf 16KB (8x512 floats: only [.][0..63] used — pad forces 2xLDS > 160KB
// so the HW cannot co-schedule 2 blocks on one CU).
// ---------------------------------------------------------------------------
__global__ __launch_bounds__(512, 1)
void caps_fused(const float4* __restrict__ Wv, const float4* __restrict__ Xv,
                float* __restrict__ vsum, __half* __restrict__ partials,
                float* __restrict__ out, unsigned* __restrict__ gbar)
{
    __shared__ __align__(16) unsigned char sWt[WIL * ICH];   // 66560 B
    __shared__ __align__(16) unsigned char sX[4096];         // 32b x 8il x 16B
    __shared__ float rbuf[8][512];                           // 16384 B (pad)

    const int tid = threadIdx.x;
    const int bid = blockIdx.x;
    const int i0  = bid * ICH;

    // ---- stage W: fp32 global -> f16 LDS in pass layout ----
    // slot (il, d&7 row, s=2j+dh) holds W[j, i0+il, d, k=0..7] as 8 halves.
#pragma unroll
    for (int it = 0; it < 16; ++it) {
        const int f  = it * 512 + tid;          // [0, 8192) float4s
        const int q4 = f & 31;                  // float4 within (j,il) row
        const int il = (f >> 5) & 7;
        const int jj = f >> 8;
        const float4 w = Wv[((size_t)jj * ICAP + (i0 + il)) * 32 + q4];
        ushort4 h;
        h.x = __half_as_ushort(__float2half(w.x));
        h.y = __half_as_ushort(__float2half(w.y));
        h.z = __half_as_ushort(__float2half(w.z));
        h.w = __half_as_ushort(__float2half(w.w));
        const int d   = q4 >> 1;
        const int sub = q4 & 1;
        *reinterpret_cast<ushort4*>(sWt + il * WIL + (d & 7) * WROW
                                    + (2 * jj + (d >> 3)) * 16 + sub * 8) = h;
    }
    // ---- stage x: fp32 global -> f16 LDS, slot (b*8+il)*16B = x[b,i,0..7] ----
    {
        const int k4 = tid & 1, il = (tid >> 1) & 7, b = tid >> 4;
        const float4 w = Xv[((size_t)b * ICAP + (i0 + il)) * 2 + k4];
        ushort4 h;
        h.x = __half_as_ushort(__float2half(w.x));
        h.y = __half_as_ushort(__float2half(w.y));
        h.z = __half_as_ushort(__float2half(w.z));
        h.w = __half_as_ushort(__float2half(w.w));
        *reinterpret_cast<ushort4*>(sX + (b * 8 + il) * 16 + k4 * 8) = h;
    }
    __syncthreads();

    const int wave = tid >> 6, lane = tid & 63;
    const int j = lane & 31, dh = lane >> 5;
    float vacc = 0.f;                            // wave-0: running vsum[e]

#pragma unroll
    for (int r = 0; r < 3; ++r) {
        const bool first = (r == 0);             // constant after unroll
        float vs[4][8], sacc[4][8];
#pragma unroll
        for (int bb = 0; bb < 4; ++bb) {
            const int b = wave + 8 * bb;
            if (!first) {
                const float* vp = vsum + b * JD + j * 16 + dh * 8;
                const float4 a  = *reinterpret_cast<const float4*>(vp);
                const float4 bq = *reinterpret_cast<const float4*>(vp + 4);
                vs[bb][0]=a.x; vs[bb][1]=a.y; vs[bb][2]=a.z; vs[bb][3]=a.w;
                vs[bb][4]=bq.x; vs[bb][5]=bq.y; vs[bb][6]=bq.z; vs[bb][7]=bq.w;
            }
#pragma unroll
            for (int q = 0; q < 8; ++q) sacc[bb][q] = 0.f;
        }

#pragma unroll
        for (int il = 0; il < ICH; ++il) {
            H8 w8[8];
#pragma unroll
            for (int cc = 0; cc < 8; ++cc)
                w8[cc].i4 = *reinterpret_cast<const int4*>(
                    sWt + il * WIL + cc * WROW + (2 * j + dh) * 16);
#pragma unroll
            for (int bb = 0; bb < 4; ++bb) {
                const int b = wave + 8 * bb;
                H8 xv;
                xv.i4 = *reinterpret_cast<const int4*>(sX + (b * 8 + il) * 16);

                float u[8], tpart = 0.f;
#pragma unroll
                for (int q = 0; q < 8; ++q) {
                    float acc = FDOT2(w8[q].h[0], xv.h[0], 0.f);
                    acc = FDOT2(w8[q].h[1], xv.h[1], acc);
                    acc = FDOT2(w8[q].h[2], xv.h[2], acc);
                    acc = FDOT2(w8[q].h[3], xv.h[3], acc);
                    u[q] = acc;
                    if (!first) tpart = fmaf(acc, vs[bb][q], tpart);
                }
                float c;
                if (first) {
                    c = 0.03125f;                // softmax(0) over 32 j's
                } else {
                    const float t = tpart + __shfl_xor(tpart, 32);
                    const float e = __expf(t);
                    float se = e;
#pragma unroll
                    for (int off = 1; off <= 16; off <<= 1)
                        se += __shfl_xor(se, off);
                    c = e * FAST_RCP(se);
                }
#pragma unroll
                for (int q = 0; q < 8; ++q)
                    sacc[bb][q] = fmaf(c, u[q], sacc[bb][q]);
            }
        }

        // fp16 partial slice, disjoint per block
        __half* pout = partials + (size_t)bid * S_ELEMS;
#pragma unroll
        for (int bb = 0; bb < 4; ++bb) {
            const int b = wave + 8 * bb;
            union { int4 v; __half2 h[4]; } pk;
#pragma unroll
            for (int q = 0; q < 4; ++q)
                pk.h[q] = __floats2half2_rn(sacc[bb][2 * q], sacc[bb][2 * q + 1]);
            *reinterpret_cast<int4*>(pout + b * JD + j * 16 + dh * 8) = pk.v;
        }

        gsync(gbar, 2 * r + 1, bid, tid);

        // ---- reduce: block owns e in [bid*64, bid*64+64) ----
        {
            const int e = bid * 64 + lane;
            float s = 0.f;
            const __half* p = partials + (size_t)wave * 32 * S_ELEMS + e;
#pragma unroll
            for (int n = 0; n < 32; ++n)
                s += __half2float(p[(size_t)n * S_ELEMS]);
            rbuf[wave][lane] = s;
            __syncthreads();
            if (wave == 0) {
                s = 0.f;
#pragma unroll
                for (int k = 0; k < 8; ++k) s += rbuf[k][lane];
                float n2 = s * s;
#pragma unroll
                for (int off = 1; off <= 8; off <<= 1)
                    n2 += __shfl_xor(n2, off);
                const float scale = n2 * FAST_RCP(1.f + n2) * FAST_RSQ(n2 + EPSQ);
                const float v = s * scale;
                if (r == 2) {
                    out[e] = v;
                } else {
                    vacc += v;                   // vsum = sum of v's so far
                    vsum[e] = vacc;
                }
            }
        }
        if (r < 2) gsync(gbar, 2 * r + 2, bid, tid);
    }
}

extern "C" void kernel_launch(void* const* d_in, const int* in_sizes, int n_in,
                              void* d_out, int out_size, void* d_ws, size_t ws_size,
                              hipStream_t stream) {
    const float* x = (const float*)d_in[0];   // [32,2048,8]
    const float* W = (const float*)d_in[1];   // [32,2048,16,8]
    float* out = (float*)d_out;               // [32,32,16]

    // ws: vsum 64KB | partials fp16 8.39MB | gbar 33KB
    float*    vsum     = (float*)d_ws;
    __half*   partials = (__half*)((char*)d_ws + 65536);
    unsigned* gbar     = (unsigned*)((char*)partials + (size_t)NBP * S_ELEMS * 2);

    // zero barrier state (flag line + 256 arrival slots)
    hipMemsetAsync(gbar, 0, GBAR_WORDS * sizeof(unsigned), stream);

    caps_fused<<<NBP, 512, 0, stream>>>((const float4*)W, (const float4*)x,
                                        vsum, partials, out, gbar);
}